// Round 4
// baseline (334.285 us; speedup 1.0000x reference)
//
#include <hip/hip_runtime.h>
#include <hip/hip_bf16.h>

#define NB 128        // batch B
#define NMEM 100000   // N
#define ND 128        // D
constexpr float T_INV = 1.0f / 0.07f;

constexpr int LROW = ND + 8;                     // 136 bf16 = 272 B LDS rows
constexpr int TILE = 128;                        // feats rows per tile
constexpr int NT = (NMEM + TILE - 1) / TILE;     // 782 tiles
constexpr int C4FULL = TILE * 129 / 4;           // 4128 float4 per full tile
constexpr int NIT = 17;                          // staging float4 per thread
constexpr int ZSTRIDE = 16;
constexpr int GRID = 512;                        // persistent: 2 blocks/CU

typedef __attribute__((ext_vector_type(8))) __bf16 bf16x8;
typedef __attribute__((ext_vector_type(4))) float f32x4;
struct bf4 { __bf16 a, b, c, d; };

// A-frag: A[m=lane&15][k=(lane>>4)*8+j]; B-frag: B[n=lane&15][k=(lane>>4)*8+j]
// C/D: col(n)=lane&15, row(m)=(lane>>4)*4+reg   [HW-verified m89/m91]
template<bool PASS2>
__global__ __launch_bounds__(256, 2) void nce_pass(
    const float* __restrict__ x,
    const int* __restrict__ labels,
    const float* __restrict__ mem_da,
    float* __restrict__ zbuf,
    int* __restrict__ ctr,
    float* __restrict__ out,
    float* __restrict__ maskout)
{
  __shared__ __bf16 xs[NB * LROW];     // 34816 B
  __shared__ __bf16 fs[TILE * LROW];   // 34816 B
  __shared__ float lbl_n[TILE];
  __shared__ float lbl_b[NB];
  __shared__ float rz[NB];
  __shared__ float zl[NB];
  __shared__ int cur;                  // ~71.5 KB total -> 2 blocks/CU

  const int tid = threadIdx.x;

  // ---- stage x once: 64 KB f32 -> bf16 LDS ----
  const float4* x4 = (const float4*)x;
  float4 xv[16];
  #pragma unroll
  for (int i = 0; i < 16; ++i) xv[i] = x4[tid + i * 256];
  #pragma unroll
  for (int i = 0; i < 16; ++i) {
    int g4 = tid + i * 256;
    *(bf4*)&xs[(g4 >> 5) * LROW + (g4 & 31) * 4] =
        bf4{(__bf16)xv[i].x, (__bf16)xv[i].y, (__bf16)xv[i].z, (__bf16)xv[i].w};
  }
  if (tid < NB) {
    lbl_b[tid] = (float)labels[tid];
    if (PASS2) rz[tid] = 1.0f / zbuf[tid * ZSTRIDE];
    else zl[tid] = 0.f;
  }

  if (tid == 0) cur = atomicAdd(ctr, 1);
  __syncthreads();                     // xs, lbl_b, rz/zl, cur visible
  int t = cur;

  float4 fv[NIT];
  auto prefetch = [&](int tt) {
    const float4* f4 = (const float4*)(mem_da + (size_t)tt * (TILE * 129));
    const int c4 = (tt == NT - 1) ? (NMEM - tt * TILE) * 129 / 4 : C4FULL;
    #pragma unroll
    for (int i = 0; i < NIT; ++i) {
      int idx = tid + i * 256;
      fv[i] = f4[idx < c4 ? idx : 0];
    }
  };
  if (t < NT) prefetch(t);

  const int wid = tid >> 6, lane = tid & 63, q = lane >> 4, l16 = lane & 15;

  while (t < NT) {
    // ---- convert fv -> fs (de-interleave stride-129), lbl_n ----
    const int rows = min(TILE, NMEM - t * TILE);
    const int c4 = rows * 129 / 4;
    #pragma unroll
    for (int i = 0; i < NIT; ++i) {
      int idx = tid + i * 256;
      if (idx < c4) {
        unsigned g = 4u * (unsigned)idx;
        unsigned r = g / 129u;
        unsigned cc = g - r * 129u;
        float4 v = fv[i];
        #pragma unroll
        for (int c = 0; c < 4; ++c) {
          float val = (&v.x)[c];
          if (cc == 0) lbl_n[r] = val;
          else fs[r * LROW + (cc - 1)] = (__bf16)val;
          if (++cc == 129u) { cc = 0; ++r; }
        }
      }
    }
    if (tid == 0) cur = atomicAdd(ctr, 1);
    __syncthreads();                   // fs + cur ready
    const int tn = cur;
    if (tn < NT) prefetch(tn);         // next tile's loads fly during MFMA

    // ---- MFMA + epilogue (wave wid owns 32-row sub-tile wid) ----
    const int ntb = rows >> 5;         // 4, last tile 1
    if (wid < ntb) {
      f32x4 acc[8][2];
      #pragma unroll
      for (int mt = 0; mt < 8; ++mt) {
        acc[mt][0] = (f32x4){0.f, 0.f, 0.f, 0.f};
        acc[mt][1] = (f32x4){0.f, 0.f, 0.f, 0.f};
      }
      #pragma unroll
      for (int kc = 0; kc < 4; ++kc) {
        const int ko = kc * 32 + q * 8;
        bf16x8 b0 = *(const bf16x8*)&fs[(wid * 32 + l16) * LROW + ko];
        bf16x8 b1 = *(const bf16x8*)&fs[(wid * 32 + 16 + l16) * LROW + ko];
        #pragma unroll
        for (int mt = 0; mt < 8; ++mt) {
          bf16x8 a = *(const bf16x8*)&xs[(mt * 16 + l16) * LROW + ko];
          acc[mt][0] = __builtin_amdgcn_mfma_f32_16x16x32_bf16(a, b0, acc[mt][0], 0, 0, 0);
          acc[mt][1] = __builtin_amdgcn_mfma_f32_16x16x32_bf16(a, b1, acc[mt][1], 0, 0, 0);
        }
      }
      const size_t nb0 = (size_t)t * TILE + wid * 32 + l16;
      if (!PASS2) {
        float ln0 = lbl_n[wid * 32 + l16];
        float ln1 = lbl_n[wid * 32 + 16 + l16];
        #pragma unroll
        for (int mt = 0; mt < 8; ++mt) {
          #pragma unroll
          for (int r = 0; r < 4; ++r) {
            int m = mt * 16 + q * 4 + r;
            float lb = lbl_b[m];
            size_t base = (size_t)m * NMEM + nb0;
            maskout[base]      = (ln0 == lb) ? 1.0f : 0.0f;
            maskout[base + 16] = (ln1 == lb) ? 1.0f : 0.0f;
            float v = __expf(acc[mt][0][r] * T_INV) + __expf(acc[mt][1][r] * T_INV);
            v += __shfl_xor(v, 1);
            v += __shfl_xor(v, 2);
            v += __shfl_xor(v, 4);
            v += __shfl_xor(v, 8);
            if (l16 == 0) atomicAdd(&zl[m], v);
          }
        }
      } else {
        #pragma unroll
        for (int mt = 0; mt < 8; ++mt) {
          #pragma unroll
          for (int r = 0; r < 4; ++r) {
            int m = mt * 16 + q * 4 + r;
            float rzm = rz[m];
            size_t base = (size_t)m * NMEM + nb0;
            out[base]      = __expf(acc[mt][0][r] * T_INV) * rzm;
            out[base + 16] = __expf(acc[mt][1][r] * T_INV) * rzm;
          }
        }
      }
    }
    __syncthreads();                   // fs fully consumed
    t = tn;
  }

  if (!PASS2) {
    if (tid < NB) atomicAdd(&zbuf[tid * ZSTRIDE], zl[tid]);
  }
}

extern "C" void kernel_launch(void* const* d_in, const int* in_sizes, int n_in,
                              void* d_out, int out_size, void* d_ws, size_t ws_size,
                              hipStream_t stream) {
  const float* x      = (const float*)d_in[0];
  const int* labels   = (const int*)d_in[2];
  const float* mem_da = (const float*)d_in[3];
  float* out     = (float*)d_out;
  float* maskout = out + (size_t)NB * NMEM;
  float* zbuf    = (float*)d_ws;                    // 128*16 floats = 8192 B
  int* ctrA      = (int*)((char*)d_ws + 8192);
  int* ctrB      = (int*)((char*)d_ws + 8192 + 64); // separate cache lines

  hipMemsetAsync(d_ws, 0, 8192 + 128, stream);      // zbuf + both counters
  nce_pass<false><<<GRID, 256, 0, stream>>>(x, labels, mem_da, zbuf, ctrA, nullptr, maskout);
  nce_pass<true ><<<GRID, 256, 0, stream>>>(x, labels, mem_da, zbuf, ctrB, out, nullptr);
}

// Round 5
// 207.715 us; speedup vs baseline: 1.6093x; 1.6093x over previous
//
#include <hip/hip_runtime.h>
#include <hip/hip_bf16.h>

#define NB 128        // batch B
#define NMEM 100000   // N
#define ND 128        // D
constexpr float T_INV = 1.0f / 0.07f;

constexpr int LROW = ND + 8;              // xs LDS row: 136 bf16 = 272 B
constexpr int NTW = NMEM / 16;            // 6250 wave-tiles of 16 n-rows (exact)
constexpr int GRID = 512;                 // 2 blocks/CU -> 8 waves/CU
constexpr int NWAVES = GRID * 4;          // 2048
constexpr int ZSTRIDE = 16;               // zbuf slots 64 B apart

typedef __attribute__((ext_vector_type(8))) __bf16 bf16x8;
typedef __attribute__((ext_vector_type(4))) float f32x4;
struct bf4 { __bf16 a, b, c, d; };

// A-frag: A[m=lane&15][k=(lane>>4)*8+j]; B-frag: B[n=lane&15][k=(lane>>4)*8+j]
// C/D: col(n)=lane&15, row(m)=(lane>>4)*4+reg   [HW-verified m89/m91]
template<bool PASS2>
__global__ __launch_bounds__(256, 2) void nce_wave(
    const float* __restrict__ x,
    const int* __restrict__ labels,
    const float* __restrict__ mem_da,
    float* __restrict__ zbuf,
    float* __restrict__ out,
    float* __restrict__ maskout)
{
  __shared__ __bf16 xs[NB * LROW];   // 34816 B
  __shared__ float aux[NB];          // pass1: lbl_b; pass2: 1/Z
  __shared__ float zl[NB];           // pass1 block Z partials

  const int tid = threadIdx.x;

  // ---- one-time stage: x -> bf16 LDS, aux, zl ----
  const float4* x4 = (const float4*)x;
  float4 xv[16];
  #pragma unroll
  for (int i = 0; i < 16; ++i) xv[i] = x4[tid + i * 256];
  #pragma unroll
  for (int i = 0; i < 16; ++i) {
    int g4 = tid + i * 256;
    *(bf4*)&xs[(g4 >> 5) * LROW + (g4 & 31) * 4] =
        bf4{(__bf16)xv[i].x, (__bf16)xv[i].y, (__bf16)xv[i].z, (__bf16)xv[i].w};
  }
  if (tid < NB) {
    if (PASS2) aux[tid] = 1.0f / zbuf[tid * ZSTRIDE];
    else { aux[tid] = (float)labels[tid]; zl[tid] = 0.f; }
  }
  __syncthreads();                   // the ONLY barrier before the wave loop

  const int wid = tid >> 6, lane = tid & 63, q = lane >> 4, l16 = lane & 15;
  const int wgid = blockIdx.x * 4 + wid;

  // per-m constants for this lane's 32 output rows: m = mt*16 + q*4 + r
  f32x4 am[8];                       // lbl_b[m] (pass1) or 1/Z[m] (pass2)
  #pragma unroll
  for (int mt = 0; mt < 8; ++mt) am[mt] = *(const f32x4*)&aux[mt * 16 + q * 4];

  f32x4 zacc[8];
  #pragma unroll
  for (int mt = 0; mt < 8; ++mt) zacc[mt] = (f32x4){0.f, 0.f, 0.f, 0.f};

  // ---- barrier-free wave loop: tiles wgid, wgid+2048, ... ----
  for (int t = wgid; t < NTW; t += NWAVES) {
    const float* rowp = mem_da + (size_t)(t * 16 + l16) * 129;   // lane's n-row
    float ln;
    if (!PASS2) ln = rowp[0];                                     // bank label
    // B fragments: 8 feature floats per kc, direct global -> regs
    float bf[4][8];
    #pragma unroll
    for (int kc = 0; kc < 4; ++kc)
      __builtin_memcpy(&bf[kc][0], rowp + 1 + kc * 32 + q * 8, 32);
    bf16x8 bb[4];
    #pragma unroll
    for (int kc = 0; kc < 4; ++kc)
      #pragma unroll
      for (int j = 0; j < 8; ++j) bb[kc][j] = (__bf16)bf[kc][j];

    f32x4 acc[8];
    #pragma unroll
    for (int mt = 0; mt < 8; ++mt) acc[mt] = (f32x4){0.f, 0.f, 0.f, 0.f};
    #pragma unroll
    for (int kc = 0; kc < 4; ++kc) {
      const int ko = kc * 32 + q * 8;
      #pragma unroll
      for (int mt = 0; mt < 8; ++mt) {
        bf16x8 a = *(const bf16x8*)&xs[(mt * 16 + l16) * LROW + ko];
        acc[mt] = __builtin_amdgcn_mfma_f32_16x16x32_bf16(a, bb[kc], acc[mt], 0, 0, 0);
      }
    }

    const size_t n = (size_t)t * 16 + l16;
    #pragma unroll
    for (int mt = 0; mt < 8; ++mt) {
      #pragma unroll
      for (int r = 0; r < 4; ++r) {
        const size_t off = (size_t)(mt * 16 + q * 4 + r) * NMEM + n;
        if (!PASS2) {
          zacc[mt][r] += __expf(acc[mt][r] * T_INV);
          maskout[off] = (ln == am[mt][r]) ? 1.0f : 0.0f;
        } else {
          out[off] = __expf(acc[mt][r] * T_INV) * am[mt][r];
        }
      }
    }
  }

  // ---- pass1 finalize: butterfly within 16-lane groups -> LDS -> global ----
  if (!PASS2) {
    #pragma unroll
    for (int mt = 0; mt < 8; ++mt) {
      #pragma unroll
      for (int r = 0; r < 4; ++r) {
        float v = zacc[mt][r];
        v += __shfl_xor(v, 1);
        v += __shfl_xor(v, 2);
        v += __shfl_xor(v, 4);
        v += __shfl_xor(v, 8);
        if (l16 == 0) atomicAdd(&zl[mt * 16 + q * 4 + r], v);
      }
    }
    __syncthreads();
    if (tid < NB) atomicAdd(&zbuf[tid * ZSTRIDE], zl[tid]);
  }
}

extern "C" void kernel_launch(void* const* d_in, const int* in_sizes, int n_in,
                              void* d_out, int out_size, void* d_ws, size_t ws_size,
                              hipStream_t stream) {
  const float* x      = (const float*)d_in[0];
  const int* labels   = (const int*)d_in[2];
  const float* mem_da = (const float*)d_in[3];
  float* out     = (float*)d_out;
  float* maskout = out + (size_t)NB * NMEM;
  float* zbuf    = (float*)d_ws;     // 128*16 floats = 8192 B

  hipMemsetAsync(zbuf, 0, NB * ZSTRIDE * sizeof(float), stream);
  nce_wave<false><<<GRID, 256, 0, stream>>>(x, labels, mem_da, zbuf, nullptr, maskout);
  nce_wave<true ><<<GRID, 256, 0, stream>>>(x, labels, mem_da, zbuf, out, nullptr);
}